// Round 14
// baseline (298.083 us; speedup 1.0000x reference)
//
#include <hip/hip_runtime.h>
#include <hip/hip_bf16.h>
#include <hip/hip_cooperative_groups.h>

namespace cg = cooperative_groups;

typedef short short8 __attribute__((ext_vector_type(8)));
typedef float f32x4 __attribute__((ext_vector_type(4)));
typedef const void __attribute__((address_space(1))) as1_void;
typedef void __attribute__((address_space(3))) as3_void;

// hardware trig: input in revolutions (D = sin/cos(S0 * 2pi)), already in [0,1)
__device__ __forceinline__ float sin_rev(float r) {
  float o; asm("v_sin_f32 %0, %1" : "=v"(o) : "v"(r)); return o;
}
__device__ __forceinline__ float cos_rev(float r) {
  float o; asm("v_cos_f32 %0, %1" : "=v"(o) : "v"(r)); return o;
}

#define INV4096 0.000244140625f
#define INV16   0.0625f
#define SPLITK  8
#define KCHUNK  256   // 2048 / SPLITK

// ---------------------------------------------------------------------------
// Phase 1 task: [0,32) t_mod ; [32,1056) Hermitian-fold transpose
// ---------------------------------------------------------------------------
__device__ __forceinline__ void prep_task(int bid, int tid, char* smem,
                                          const float* __restrict__ t_emb,
                                          const float* __restrict__ dr,
                                          const float* __restrict__ di,
                                          float* __restrict__ Sr,
                                          float* __restrict__ Si,
                                          const float* __restrict__ x,
                                          __hip_bfloat16* __restrict__ E,
                                          __hip_bfloat16* __restrict__ O,
                                          float* __restrict__ Xr256p,
                                          float* __restrict__ x2048f) {
  float* sf    = (float*)smem;
  float* tileA = sf;           // [64][65]
  float* tileB = sf + 4160;    // [64][65]
  float* te    = sf + 8320;    // [256]
  float* red   = sf + 8576;    // [4][64]
  float* xm    = sf + 8832;    // [64]

  if (bid < 32) {
    int b = bid;
    te[tid] = t_emb[b * 256 + tid];
    __syncthreads();
    for (int m = tid; m < 257; m += 256) {
      float ar = 0.f, ai = 0.f;
      for (int t = 0; t < 256; ++t) {
        float e = te[t];
        ar += e * dr[t * 257 + m];
        ai += e * di[t * 257 + m];
      }
      float c = (m == 0 ? 1.0f : 2.0f) * (1.0f / 4096.0f);
      Sr[b * 257 + m] = ar * c;
      Si[b * 257 + m] = ai * c;
    }
  } else {
    int idx = bid - 32;           // 0..1023
    int nt = idx & 31;            // n-tile 0..31
    int b  = idx >> 5;            // batch
    int n0 = nt * 64;
    int m0r = (63 - nt) * 64;     // mirror tile rows
#pragma unroll
    for (int it = 0; it < 4; ++it) {
      int c = it * 256 + tid;
      int r = c >> 4, i4 = (c & 15) * 4;
      float4 v = *(const float4*)&x[((size_t)b * 4096 + n0 + r) * 64 + i4];
      tileA[r * 65 + i4 + 0] = v.x; tileA[r * 65 + i4 + 1] = v.y;
      tileA[r * 65 + i4 + 2] = v.z; tileA[r * 65 + i4 + 3] = v.w;
      float4 w = *(const float4*)&x[((size_t)b * 4096 + m0r + r) * 64 + i4];
      tileB[r * 65 + i4 + 0] = w.x; tileB[r * 65 + i4 + 1] = w.y;
      tileB[r * 65 + i4 + 2] = w.z; tileB[r * 65 + i4 + 3] = w.w;
    }
    if (tid < 64) xm[tid] = (nt > 0) ? x[((size_t)b * 4096 + (4096 - n0)) * 64 + tid] : 0.f;
    __syncthreads();
#pragma unroll
    for (int it = 0; it < 2; ++it) {
      int c  = it * 256 + tid;
      int i  = c >> 3;
      int ch = c & 7;
      union { short8 v; unsigned short u[8]; } pe, po;
#pragma unroll
      for (int jj = 0; jj < 8; ++jj) {
        int j = ch * 8 + jj;
        float a = tileA[j * 65 + i];
        float mir = (j == 0) ? xm[i] : tileB[(64 - j) * 65 + i];
        __hip_bfloat16 he = __float2bfloat16(a + mir);
        __hip_bfloat16 ho = __float2bfloat16(a - mir);
        pe.u[jj] = *(unsigned short*)&he;
        po.u[jj] = *(unsigned short*)&ho;
      }
      size_t base = ((size_t)b * 64 + i) * 2048 + n0 + ch * 8;
      *(short8*)&E[base] = pe.v;
      *(short8*)&O[base] = po.v;
    }
    {
      int i = tid & 63, g = tid >> 6;
      float acc = 0.f;
#pragma unroll
      for (int j = 0; j < 16; ++j) {
        float w = cos_rev((float)j * INV16);
        acc += w * (tileA[(g * 16 + j) * 65 + i] + tileB[(g * 16 + j) * 65 + i]);
      }
      red[g * 64 + i] = acc;
    }
    __syncthreads();
    if (tid < 64) {
      Xr256p[((size_t)b * 32 + nt) * 64 + tid] =
          red[tid] + red[64 + tid] + red[128 + tid] + red[192 + tid];
      if (nt == 31) x2048f[b * 64 + tid] = tileB[0 * 65 + tid];
    }
  }
}

// ---------------------------------------------------------------------------
// GEMM core with GENERATED A-operand (trig basis) + loaded B (m97 + T2 swizzle)
// MODE 1: A = F2 [512][2048]; MODE 2: A = Gm2 [2048][512]
// ---------------------------------------------------------------------------
template <int NF, int MODE>
__device__ __forceinline__ void stage_genT(int m0, int kt,
                                           const __hip_bfloat16* __restrict__ B, int ldb, int n0,
                                           __hip_bfloat16* As, __hip_bfloat16* Bs, int tid) {
#pragma unroll
  for (int j = 0; j < NF; ++j) {
    int c   = j * 256 + tid;
    int row = c >> 3;
    int chg = (c & 7) ^ (row & 7);
    const __hip_bfloat16* gb = B + (size_t)(n0 + row) * ldb + kt + chg * 8;
    __hip_bfloat16* lb = Bs + (size_t)(j * 256 + (tid & 192)) * 8;
    __builtin_amdgcn_global_load_lds((as1_void*)gb, (as3_void*)lb, 16, 0, 0);
  }
#pragma unroll
  for (int j = 0; j < 4; ++j) {
    int c   = j * 256 + tid;
    int row = c >> 3;
    int chg = (c & 7) ^ (row & 7);
    int gr  = m0 + row;
    union { short8 v; unsigned short u[8]; } pk;
#pragma unroll
    for (int jj = 0; jj < 8; ++jj) {
      int col = kt + chg * 8 + jj;
      float v;
      if (MODE == 1) {
        int m  = (gr < 256) ? gr : (gr - 255);
        int ph = (m * col) & 4095;
        v = (gr < 256) ?  cos_rev((float)ph * INV4096)
                       : -sin_rev((float)ph * INV4096);
      } else {
        int k  = (col < 256) ? col : (col - 255);
        int ph = (gr * k) & 4095;
        v = (col < 256) ? cos_rev((float)ph * INV4096)
                        : sin_rev((float)ph * INV4096);
      }
      __hip_bfloat16 h = __float2bfloat16(v);
      pk.u[jj] = *(unsigned short*)&h;
    }
    *(short8*)&As[(size_t)c * 8] = pk.v;
  }
}

template <int NF>
__device__ __forceinline__ void compute_stepT(const __hip_bfloat16* As, const __hip_bfloat16* Bs,
                                              int wr, int wc, int fr, int fq,
                                              f32x4 acc[4][NF]) {
#pragma unroll
  for (int kk = 0; kk < 2; ++kk) {
    short8 av[4], bv[NF];
#pragma unroll
    for (int m = 0; m < 4; ++m) {
      int row  = wr + m * 16 + fr;
      int slot = (fq + kk * 4) ^ (row & 7);
      av[m] = *(const short8*)(As + row * 64 + slot * 8);
    }
#pragma unroll
    for (int n = 0; n < NF; ++n) {
      int row  = wc + n * 16 + fr;
      int slot = (fq + kk * 4) ^ (row & 7);
      bv[n] = *(const short8*)(Bs + row * 64 + slot * 8);
    }
#pragma unroll
    for (int m = 0; m < 4; ++m)
#pragma unroll
      for (int n = 0; n < NF; ++n)
        acc[m][n] = __builtin_amdgcn_mfma_f32_16x16x32_bf16(av[m], bv[n], acc[m][n], 0, 0, 0);
  }
}

template <int NF, int MODE>
__device__ __forceinline__ void gemm_coreT(int m0,
                                           const __hip_bfloat16* __restrict__ B, int ldb, int n0,
                                           int k0, int ksteps,
                                           __hip_bfloat16* As, __hip_bfloat16* Bs,
                                           f32x4 acc[4][NF]) {
  const int tid  = threadIdx.x;
  const int lane = tid & 63;
  const int wv   = tid >> 6;
  const int wr   = (wv >> 1) * 64;
  const int wc   = (wv & 1) * (NF * 16);
  const int fr   = lane & 15;
  const int fq   = lane >> 4;

  for (int ks = 0; ks < ksteps; ++ks) {
    stage_genT<NF, MODE>(m0, k0 + ks * 64, B, ldb, n0, As, Bs, tid);
    __syncthreads();
    compute_stepT<NF>(As, Bs, wr, wc, fr, fq, acc);
    __syncthreads();
  }
}

// Phase 2 task: GEMM1 (folded), C1[row][z][bi] bf16 = F2gen @ {E|O}^T
__device__ __forceinline__ void gemm1_task(int t, char* smem,
                                           const __hip_bfloat16* __restrict__ E,
                                           const __hip_bfloat16* __restrict__ O,
                                           __hip_bfloat16* __restrict__ C1) {
  __hip_bfloat16* As = (__hip_bfloat16*)smem;            // 8192 elems
  __hip_bfloat16* Bs = (__hip_bfloat16*)smem + 8192;     // 8192 elems
  int z   = t >> 6;             // 0..7
  int rem = t & 63;
  int m0  = (rem >> 4) * 128;
  int n0  = (rem & 15) * 128;
  int k0  = z * KCHUNK;
  const __hip_bfloat16* B = (m0 < 256) ? E : O;
  f32x4 acc[4][4];
#pragma unroll
  for (int m = 0; m < 4; ++m)
#pragma unroll
    for (int n = 0; n < 4; ++n)
#pragma unroll
      for (int r = 0; r < 4; ++r) acc[m][n][r] = 0.f;

  gemm_coreT<4, 1>(m0, B, 2048, n0, k0, KCHUNK >> 6, As, Bs, acc);

  const int lane = threadIdx.x & 63;
  const int wv   = threadIdx.x >> 6;
  const int wr   = (wv >> 1) * 64, wc = (wv & 1) * 64;
  const int fr   = lane & 15, fq = lane >> 4;
#pragma unroll
  for (int m = 0; m < 4; ++m)
#pragma unroll
    for (int n = 0; n < 4; ++n)
#pragma unroll
      for (int j = 0; j < 4; ++j) {
        int row = m0 + wr + m * 16 + fq * 4 + j;
        int col = n0 + wc + n * 16 + fr;
        C1[((size_t)row * SPLITK + z) * 2048 + col] = __float2bfloat16(acc[m][n][j]);
      }
}

// Phase 3 task: mode mix. t = k + 257*q
__device__ __forceinline__ void mix_task(int t, int tid, char* smem,
                                         const __hip_bfloat16* __restrict__ C1,
                                         const float* __restrict__ Xr256p,
                                         const float* __restrict__ x2048f,
                                         const float* __restrict__ Wr,
                                         const float* __restrict__ Wi,
                                         const float* __restrict__ Sr,
                                         const float* __restrict__ Si,
                                         __hip_bfloat16* __restrict__ Y2T,
                                         __hip_bfloat16* __restrict__ Yx) {
  float* wlr = (float*)smem;          // 4096
  float* wli = wlr + 4096;            // 4096
  float* xs  = wli + 4096;            // 2048
  const int k = t % 257;
  const int q = t / 257;

  const float* wrg = Wr + (size_t)k * 4096;
  const float* wig = Wi + (size_t)k * 4096;
  for (int c = tid; c < 1024; c += 256) {
    *(float4*)&wlr[c * 4] = *(const float4*)&wrg[c * 4];
    *(float4*)&wli[c * 4] = *(const float4*)&wig[c * 4];
  }

  {
    const int part = tid >> 7;        // 0=real, 1=imag
    const int ln   = tid & 127;       // 8 bi each -> 1024 bi
    const int bi0  = q * 1024 + ln * 8;
    float f[8] = {0.f, 0.f, 0.f, 0.f, 0.f, 0.f, 0.f, 0.f};
    if (part == 0) {
      if (k < 256) {
        const __hip_bfloat16* src = C1 + (size_t)k * SPLITK * 2048 + bi0;
        for (int z = 0; z < SPLITK; ++z) {
          short8 v = *(const short8*)(src + (size_t)z * 2048);
#pragma unroll
          for (int j = 0; j < 8; ++j) {
            unsigned short u = (unsigned short)v[j];
            f[j] += __bfloat162float(*(__hip_bfloat16*)&u);
          }
        }
        float par = (k & 1) ? -1.f : 1.f;   // cos(k*pi) * x[2048]
#pragma unroll
        for (int j = 0; j < 8; ++j) f[j] += par * x2048f[bi0 + j];
      } else {
        const float* sp = Xr256p + (size_t)(bi0 >> 6) * 2048 + (bi0 & 63);
#pragma unroll 8
        for (int nt = 0; nt < 32; ++nt)
#pragma unroll
          for (int j = 0; j < 8; ++j) f[j] += sp[nt * 64 + j];
      }
    } else if (k > 0) {
      const __hip_bfloat16* src = C1 + (size_t)(255 + k) * SPLITK * 2048 + bi0;
      for (int z = 0; z < SPLITK; ++z) {
        short8 v = *(const short8*)(src + (size_t)z * 2048);
#pragma unroll
        for (int j = 0; j < 8; ++j) {
          unsigned short u = (unsigned short)v[j];
          f[j] += __bfloat162float(*(__hip_bfloat16*)&u);
        }
      }
    }
#pragma unroll
    for (int j = 0; j < 8; ++j) xs[part * 1024 + ln * 8 + j] = f[j];
  }
  __syncthreads();

  const int o  = tid & 63;
  const int jj = tid >> 6;
  float pr[4] = {0.f, 0.f, 0.f, 0.f};
  float pi[4] = {0.f, 0.f, 0.f, 0.f};
#pragma unroll 4
  for (int i = 0; i < 64; ++i) {
    float wrv = wlr[i * 64 + o];
    float wiv = wli[i * 64 + o];
#pragma unroll
    for (int u = 0; u < 4; ++u) {
      int lb = (jj * 4 + u) * 64 + i;
      float xr = xs[lb], xi = xs[1024 + lb];
      pr[u] += xr * wrv - xi * wiv;
      pi[u] += xr * wiv + xi * wrv;
    }
  }
#pragma unroll
  for (int u = 0; u < 4; ++u) {
    int b = q * 16 + jj * 4 + u;
    float sr = Sr[b * 257 + k], si = Si[b * 257 + k];
    int bo = b * 64 + o;
    __hip_bfloat16 yr = __float2bfloat16(pr[u] * sr - pi[u] * si);
    __hip_bfloat16 yi = __float2bfloat16(pr[u] * si + pi[u] * sr);
    if (k < 256) Y2T[(size_t)bo * 512 + k] = yr;
    else         Yx[bo] = yr;
    if (k >= 1)  Y2T[(size_t)bo * 512 + 255 + k] = yi;
  }
}

// Phase 4 task: GEMM2 (folded), Gm2 generated
__device__ __forceinline__ void gemm2_task(int t, char* smem,
                                           const __hip_bfloat16* __restrict__ Y2T,
                                           const __hip_bfloat16* __restrict__ Yx,
                                           float* __restrict__ out) {
  __hip_bfloat16* As = (__hip_bfloat16*)smem;            // 8192 elems
  __hip_bfloat16* Bs = (__hip_bfloat16*)smem + 8192;     // 4096 elems
  float* red2 = (float*)(smem + 24576);                  // [4][64]
  int n0 = (t & 31) * 64;     // bo
  int m0 = (t >> 5) * 128;    // n (time), 0..1920
  f32x4 accC[4][2], accS[4][2];
#pragma unroll
  for (int m = 0; m < 4; ++m)
#pragma unroll
    for (int n = 0; n < 2; ++n)
#pragma unroll
      for (int r = 0; r < 4; ++r) { accC[m][n][r] = 0.f; accS[m][n][r] = 0.f; }

  gemm_coreT<2, 2>(m0, Y2T, 512, n0, 0,   4, As, Bs, accC);
  gemm_coreT<2, 2>(m0, Y2T, 512, n0, 256, 4, As, Bs, accS);

  const int lane = threadIdx.x & 63;
  const int wv   = threadIdx.x >> 6;
  const int wr   = (wv >> 1) * 64, wc = (wv & 1) * 32;
  const int fr   = lane & 15, fq = lane >> 4;
  float yx[2];
#pragma unroll
  for (int n = 0; n < 2; ++n)
    yx[n] = __bfloat162float(Yx[n0 + wc + n * 16 + fr]);
#pragma unroll
  for (int m = 0; m < 4; ++m)
#pragma unroll
    for (int j = 0; j < 4; ++j) {
      int row = m0 + wr + m * 16 + fq * 4 + j;   // n index 0..2047
      float g = cos_rev((float)(row & 15) * INV16);
#pragma unroll
      for (int n = 0; n < 2; ++n) {
        int col = n0 + wc + n * 16 + fr;         // bo index
        int b = col >> 6, o = col & 63;
        float vC = accC[m][n][j] + g * yx[n];
        float vS = accS[m][n][j];
        out[((size_t)b * 4096 + row) * 64 + o] = vC - vS;
        if (row > 0)
          out[((size_t)b * 4096 + (4096 - row)) * 64 + o] = vC + vS;
      }
    }

  if (m0 == 0) {
    __syncthreads();
    const int tid = threadIdx.x;
    int col = tid & 63, grp = tid >> 6;
    int bo = n0 + col;
    float s = 0.f;
    for (int k = grp * 64; k < grp * 64 + 64; ++k) {
      float v = __bfloat162float(Y2T[(size_t)bo * 512 + k]);
      s += (k & 1) ? -v : v;
    }
    red2[grp * 64 + col] = s;
    __syncthreads();
    if (tid < 64) {
      int bo2 = n0 + tid;
      float alt = red2[tid] + red2[64 + tid] + red2[128 + tid] + red2[192 + tid]
                + __bfloat162float(Yx[bo2]);
      int b = bo2 >> 6, o = bo2 & 63;
      out[((size_t)b * 4096 + 2048) * 64 + o] = alt;
    }
  }
}

// ---------------------------------------------------------------------------
// Cooperative mega-kernel. __launch_bounds__(256,2): 2 waves/EU min =>
// VGPR capped at 256 => >=2 blocks/CU => grid 512 is cooperatively launchable.
// ---------------------------------------------------------------------------
__global__ __launch_bounds__(256, 2) void mega_kernel(const float* __restrict__ t_emb,
                                                      const float* __restrict__ dr,
                                                      const float* __restrict__ di,
                                                      float* __restrict__ Sr,
                                                      float* __restrict__ Si,
                                                      const float* __restrict__ x,
                                                      __hip_bfloat16* __restrict__ E,
                                                      __hip_bfloat16* __restrict__ O,
                                                      float* __restrict__ Xr256p,
                                                      float* __restrict__ x2048f,
                                                      const float* __restrict__ Wr,
                                                      const float* __restrict__ Wi,
                                                      __hip_bfloat16* __restrict__ C1,
                                                      __hip_bfloat16* __restrict__ Y2T,
                                                      __hip_bfloat16* __restrict__ Yx,
                                                      float* __restrict__ out) {
  __shared__ __align__(16) char smem[40960];
  const int tid = threadIdx.x;
  cg::grid_group grid = cg::this_grid();

  for (int t = blockIdx.x; t < 1056; t += gridDim.x) {
    prep_task(t, tid, smem, t_emb, dr, di, Sr, Si, x, E, O, Xr256p, x2048f);
    __syncthreads();
  }
  grid.sync();
  for (int t = blockIdx.x; t < 512; t += gridDim.x) {
    gemm1_task(t, smem, E, O, C1);
    __syncthreads();
  }
  grid.sync();
  for (int t = blockIdx.x; t < 514; t += gridDim.x) {
    mix_task(t, tid, smem, C1, Xr256p, x2048f, Wr, Wi, Sr, Si, Y2T, Yx);
    __syncthreads();
  }
  grid.sync();
  for (int t = blockIdx.x; t < 512; t += gridDim.x) {
    gemm2_task(t, smem, Y2T, Yx, out);
    __syncthreads();
  }
}

// ---------------------------------------------------------------------------
// Fallback wrappers (proven 4-kernel path, ~R12 performance)
// ---------------------------------------------------------------------------
__global__ __launch_bounds__(256) void prep_sep(const float* t_emb, const float* dr,
                                                const float* di, float* Sr, float* Si,
                                                const float* x, __hip_bfloat16* E,
                                                __hip_bfloat16* O, float* Xr256p,
                                                float* x2048f) {
  __shared__ __align__(16) char smem[35840];
  prep_task(blockIdx.x, threadIdx.x, smem, t_emb, dr, di, Sr, Si, x, E, O, Xr256p, x2048f);
}
__global__ __launch_bounds__(256) void gemm1_sep(const __hip_bfloat16* E,
                                                 const __hip_bfloat16* O,
                                                 __hip_bfloat16* C1) {
  __shared__ __align__(16) char smem[32768];
  gemm1_task(blockIdx.x, smem, E, O, C1);
}
__global__ __launch_bounds__(256) void mix_sep(const __hip_bfloat16* C1, const float* Xr256p,
                                               const float* x2048f, const float* Wr,
                                               const float* Wi, const float* Sr,
                                               const float* Si, __hip_bfloat16* Y2T,
                                               __hip_bfloat16* Yx) {
  __shared__ __align__(16) char smem[40960];
  mix_task(blockIdx.x, threadIdx.x, smem, C1, Xr256p, x2048f, Wr, Wi, Sr, Si, Y2T, Yx);
}
__global__ __launch_bounds__(256) void gemm2_sep(const __hip_bfloat16* Y2T,
                                                 const __hip_bfloat16* Yx,
                                                 float* out) {
  __shared__ __align__(16) char smem[25600];
  gemm2_task(blockIdx.x, smem, Y2T, Yx, out);
}

// ---------------------------------------------------------------------------
extern "C" void kernel_launch(void* const* d_in, const int* in_sizes, int n_in,
                              void* d_out, int out_size, void* d_ws, size_t ws_size,
                              hipStream_t stream) {
  const float* x  = (const float*)d_in[0];   // (32,4096,64)
  const float* te = (const float*)d_in[1];   // (32,256)
  const float* wr = (const float*)d_in[2];   // (257,64,64)
  const float* wi = (const float*)d_in[3];
  const float* dr = (const float*)d_in[4];   // (256,257)
  const float* di = (const float*)d_in[5];
  float* out = (float*)d_out;

  char* p = (char*)d_ws;
  auto alloc = [&](size_t bytes) -> char* {
    char* r = p;
    p += (bytes + 255) & ~(size_t)255;
    return r;
  };
  __hip_bfloat16* E   = (__hip_bfloat16*)alloc(2048ull * 2048 * 2);
  __hip_bfloat16* O   = (__hip_bfloat16*)alloc(2048ull * 2048 * 2);
  float* Xr256p = (float*)alloc(32ull * 32 * 64 * 4);   // [b][nt 32][i]
  float* x2048f = (float*)alloc(2048 * 4);
  float* Sr = (float*)alloc(32 * 257 * 4);
  float* Si = (float*)alloc(32 * 257 * 4);
  __hip_bfloat16* Y2T = (__hip_bfloat16*)alloc(2048ull * 512 * 2);
  __hip_bfloat16* Yx  = (__hip_bfloat16*)alloc(2048 * 2);
  __hip_bfloat16* C1  = (__hip_bfloat16*)alloc((size_t)SPLITK * 512 * 2048 * 2);

  // --- cooperative-path feasibility (host-only queries; deterministic) ---
  bool coop = false;
  int grid = 0;
  {
    int dev = 0;
    (void)hipGetDevice(&dev);
    int supported = 0;
    if (hipDeviceGetAttribute(&supported, hipDeviceAttributeCooperativeLaunch, dev) == hipSuccess
        && supported) {
      int occ = 0;
      if (hipOccupancyMaxActiveBlocksPerMultiprocessor(&occ, (const void*)mega_kernel, 256, 0)
              == hipSuccess && occ >= 1) {
        grid = occ * 256;          // 256 CUs on MI355X
        if (grid > 512) grid = 512;
        coop = true;
      }
    }
  }

  if (coop) {
    void* args[] = {
      (void*)&te, (void*)&dr, (void*)&di, (void*)&Sr, (void*)&Si,
      (void*)&x,  (void*)&E,  (void*)&O,  (void*)&Xr256p, (void*)&x2048f,
      (void*)&wr, (void*)&wi, (void*)&C1, (void*)&Y2T, (void*)&Yx, (void*)&out
    };
    hipError_t le = hipLaunchCooperativeKernel((void*)mega_kernel, dim3(grid), dim3(256),
                                               args, 0, stream);
    if (le == hipSuccess) return;
  }

  // --- fallback: proven 4-kernel path ---
  prep_sep<<<1056, 256, 0, stream>>>(te, dr, di, Sr, Si, x, E, O, Xr256p, x2048f);
  gemm1_sep<<<512, 256, 0, stream>>>(E, O, C1);
  mix_sep<<<514, 256, 0, stream>>>(C1, Xr256p, x2048f, wr, wi, Sr, Si, Y2T, Yx);
  gemm2_sep<<<512, 256, 0, stream>>>(Y2T, Yx, out);
}

// Round 15
// 84.933 us; speedup vs baseline: 3.5096x; 3.5096x over previous
//
#include <hip/hip_runtime.h>
#include <hip/hip_bf16.h>

typedef short short8 __attribute__((ext_vector_type(8)));
typedef float f32x4 __attribute__((ext_vector_type(4)));
typedef const void __attribute__((address_space(1))) as1_void;
typedef void __attribute__((address_space(3))) as3_void;

// hardware trig: input in revolutions (D = sin/cos(S0 * 2pi)), already in [0,1)
__device__ __forceinline__ float sin_rev(float r) {
  float o; asm("v_sin_f32 %0, %1" : "=v"(o) : "v"(r)); return o;
}
__device__ __forceinline__ float cos_rev(float r) {
  float o; asm("v_cos_f32 %0, %1" : "=v"(o) : "v"(r)); return o;
}

#define INV4096 0.000244140625f
#define INV16   0.0625f

// ---------------------------------------------------------------------------
// prep_kernel, grid = 3108 blocks x 256 thr, range-partitioned roles:
//  [0,512)     F2 [512][2048] bf16: row<256: cos(m n), m=row; row>=256: -sin(m n), m=row-255
//  [512,1024)  Gm2 [2048][512] bf16: col<256: cos(n k); col>=256: +sin(n k), k=col-255
//  [1024,1056) S[b][m] = (t_emb@dense_r + i t_emb@dense_i) * c_m/4096
//  [1056,2080) Hermitian-fold transpose: E[bi][n]=x[n]+x[4096-n], O[bi][n]=x[n]-x[4096-n]
//              + Xr256p partials + x2048 row capture
//  [2080,3108) Wb[k][2][4096] bf16 <- {Wr,Wi}[k] fp32
// ---------------------------------------------------------------------------
__global__ __launch_bounds__(256) void prep_kernel(__hip_bfloat16* __restrict__ F2,
                                                   __hip_bfloat16* __restrict__ Gm2,
                                                   const float* __restrict__ t_emb,
                                                   const float* __restrict__ dr,
                                                   const float* __restrict__ di,
                                                   float* __restrict__ Sr,
                                                   float* __restrict__ Si,
                                                   const float* __restrict__ x,
                                                   __hip_bfloat16* __restrict__ E,
                                                   __hip_bfloat16* __restrict__ O,
                                                   float* __restrict__ Xr256p,
                                                   float* __restrict__ x2048f,
                                                   const float* __restrict__ Wr,
                                                   const float* __restrict__ Wi,
                                                   __hip_bfloat16* __restrict__ Wb) {
  const int bid = blockIdx.x;
  const int tid = threadIdx.x;
  __shared__ float te[256];
  __shared__ float tileA[64][65];
  __shared__ float tileB[64][65];
  __shared__ float red[4][64];
  __shared__ float xm[64];

  if (bid < 512) {
    const int row = bid;
    const int m   = (row < 256) ? row : (row - 255);
    const bool is_cos = (row < 256);
    int n0 = tid * 8;
    union { short8 v; unsigned short u[8]; } pk;
#pragma unroll
    for (int j = 0; j < 8; ++j) {
      int ph = (m * (n0 + j)) & 4095;
      float v = is_cos ?  cos_rev((float)ph * INV4096)
                       : -sin_rev((float)ph * INV4096);
      __hip_bfloat16 h = __float2bfloat16(v);
      pk.u[j] = *(unsigned short*)&h;
    }
    *(short8*)&F2[(size_t)row * 2048 + n0] = pk.v;
  } else if (bid < 1024) {
    const int gb = bid - 512;         // 0..511
    int e  = tid * 8;                 // 0..2047
    int n  = gb * 4 + (e >> 9);
    int c0 = e & 511;
    union { short8 v; unsigned short u[8]; } pk;
#pragma unroll
    for (int j = 0; j < 8; ++j) {
      int cc = c0 + j;
      int k  = (cc < 256) ? cc : (cc - 255);
      int ph = (n * k) & 4095;
      float v = (cc < 256) ? cos_rev((float)ph * INV4096)
                           : sin_rev((float)ph * INV4096);
      __hip_bfloat16 h = __float2bfloat16(v);
      pk.u[j] = *(unsigned short*)&h;
    }
    *(short8*)&Gm2[(size_t)n * 512 + c0] = pk.v;
  } else if (bid < 1056) {
    int b = bid - 1024;   // 0..31
    te[tid] = t_emb[b * 256 + tid];
    __syncthreads();
    for (int m = tid; m < 257; m += 256) {
      float ar = 0.f, ai = 0.f;
      for (int t = 0; t < 256; ++t) {
        float e = te[t];
        ar += e * dr[t * 257 + m];
        ai += e * di[t * 257 + m];
      }
      float c = (m == 0 ? 1.0f : 2.0f) * (1.0f / 4096.0f);
      Sr[b * 257 + m] = ar * c;
      Si[b * 257 + m] = ai * c;
    }
  } else if (bid < 2080) {
    int idx = bid - 1056;         // 0..1023
    int nt = idx & 31;            // n-tile 0..31
    int b  = idx >> 5;            // batch
    int n0 = nt * 64;
    int m0r = (63 - nt) * 64;     // mirror tile rows
#pragma unroll
    for (int it = 0; it < 4; ++it) {
      int c = it * 256 + tid;
      int r = c >> 4, i4 = (c & 15) * 4;
      float4 v = *(const float4*)&x[((size_t)b * 4096 + n0 + r) * 64 + i4];
      tileA[r][i4 + 0] = v.x; tileA[r][i4 + 1] = v.y;
      tileA[r][i4 + 2] = v.z; tileA[r][i4 + 3] = v.w;
      float4 w = *(const float4*)&x[((size_t)b * 4096 + m0r + r) * 64 + i4];
      tileB[r][i4 + 0] = w.x; tileB[r][i4 + 1] = w.y;
      tileB[r][i4 + 2] = w.z; tileB[r][i4 + 3] = w.w;
    }
    if (tid < 64) xm[tid] = (nt > 0) ? x[((size_t)b * 4096 + (4096 - n0)) * 64 + tid] : 0.f;
    __syncthreads();
#pragma unroll
    for (int it = 0; it < 2; ++it) {
      int c  = it * 256 + tid;
      int i  = c >> 3;
      int ch = c & 7;
      union { short8 v; unsigned short u[8]; } pe, po;
#pragma unroll
      for (int jj = 0; jj < 8; ++jj) {
        int j = ch * 8 + jj;
        float a = tileA[j][i];
        float mir = (j == 0) ? xm[i] : tileB[64 - j][i];
        __hip_bfloat16 he = __float2bfloat16(a + mir);
        __hip_bfloat16 ho = __float2bfloat16(a - mir);
        pe.u[jj] = *(unsigned short*)&he;
        po.u[jj] = *(unsigned short*)&ho;
      }
      size_t base = ((size_t)b * 64 + i) * 2048 + n0 + ch * 8;
      *(short8*)&E[base] = pe.v;
      *(short8*)&O[base] = po.v;
    }
    {
      int i = tid & 63, g = tid >> 6;
      float acc = 0.f;
#pragma unroll
      for (int j = 0; j < 16; ++j) {
        float w = cos_rev((float)j * INV16);
        acc += w * (tileA[g * 16 + j][i] + tileB[g * 16 + j][i]);
      }
      red[g][i] = acc;
    }
    __syncthreads();
    if (tid < 64) {
      Xr256p[((size_t)b * 32 + nt) * 64 + tid] =
          red[0][tid] + red[1][tid] + red[2][tid] + red[3][tid];
      if (nt == 31) x2048f[b * 64 + tid] = tileB[0][tid];
    }
  } else {
    int idx  = bid - 2080;        // 0..1027
    int k    = idx >> 2;
    int quad = idx & 3;
    const float* src = (quad < 2) ? (Wr + (size_t)k * 4096 + quad * 2048)
                                  : (Wi + (size_t)k * 4096 + (quad - 2) * 2048);
    __hip_bfloat16* dst = Wb + (size_t)k * 8192 + (quad < 2 ? quad * 2048 : 4096 + (quad - 2) * 2048);
    int e = tid * 8;
    float4 v0 = *(const float4*)&src[e];
    float4 v1 = *(const float4*)&src[e + 4];
    union { short8 v; unsigned short u[8]; } pk;
    float vv[8] = {v0.x, v0.y, v0.z, v0.w, v1.x, v1.y, v1.z, v1.w};
#pragma unroll
    for (int j = 0; j < 8; ++j) {
      __hip_bfloat16 h = __float2bfloat16(vv[j]);
      pk.u[j] = *(unsigned short*)&h;
    }
    *(short8*)&dst[e] = pk.v;
  }
}

// ---------------------------------------------------------------------------
// MFMA GEMM core, single-buffer 2-barrier, NF-templated (m97 + T2 pre-swizzle)
// ---------------------------------------------------------------------------
template <int NF>
__device__ __forceinline__ void stage_tileT(const __hip_bfloat16* __restrict__ A, int lda, int m0,
                                            const __hip_bfloat16* __restrict__ B, int ldb, int n0,
                                            int kt, __hip_bfloat16* As, __hip_bfloat16* Bs,
                                            int tid) {
#pragma unroll
  for (int j = 0; j < 4; ++j) {
    int c   = j * 256 + tid;
    int row = c >> 3;
    int chg = (c & 7) ^ (row & 7);
    const __hip_bfloat16* ga = A + (size_t)(m0 + row) * lda + kt + chg * 8;
    __hip_bfloat16* la = As + (size_t)(j * 256 + (tid & 192)) * 8;
    __builtin_amdgcn_global_load_lds((as1_void*)ga, (as3_void*)la, 16, 0, 0);
  }
#pragma unroll
  for (int j = 0; j < NF; ++j) {
    int c   = j * 256 + tid;
    int row = c >> 3;
    int chg = (c & 7) ^ (row & 7);
    const __hip_bfloat16* gb = B + (size_t)(n0 + row) * ldb + kt + chg * 8;
    __hip_bfloat16* lb = Bs + (size_t)(j * 256 + (tid & 192)) * 8;
    __builtin_amdgcn_global_load_lds((as1_void*)gb, (as3_void*)lb, 16, 0, 0);
  }
}

template <int NF>
__device__ __forceinline__ void compute_stepT(const __hip_bfloat16* As, const __hip_bfloat16* Bs,
                                              int wr, int wc, int fr, int fq,
                                              f32x4 acc[4][NF]) {
#pragma unroll
  for (int kk = 0; kk < 2; ++kk) {
    short8 av[4], bv[NF];
#pragma unroll
    for (int m = 0; m < 4; ++m) {
      int row  = wr + m * 16 + fr;
      int slot = (fq + kk * 4) ^ (row & 7);
      av[m] = *(const short8*)(As + row * 64 + slot * 8);
    }
#pragma unroll
    for (int n = 0; n < NF; ++n) {
      int row  = wc + n * 16 + fr;
      int slot = (fq + kk * 4) ^ (row & 7);
      bv[n] = *(const short8*)(Bs + row * 64 + slot * 8);
    }
#pragma unroll
    for (int m = 0; m < 4; ++m)
#pragma unroll
      for (int n = 0; n < NF; ++n)
        acc[m][n] = __builtin_amdgcn_mfma_f32_16x16x32_bf16(av[m], bv[n], acc[m][n], 0, 0, 0);
  }
}

template <int NF>
__device__ __forceinline__ void gemm_coreT(const __hip_bfloat16* __restrict__ A, int lda, int m0,
                                           const __hip_bfloat16* __restrict__ B, int ldb, int n0,
                                           int k0, int ksteps,
                                           __hip_bfloat16* As, __hip_bfloat16* Bs,
                                           f32x4 acc[4][NF]) {
  const int tid  = threadIdx.x;
  const int lane = tid & 63;
  const int wv   = tid >> 6;
  const int wr   = (wv >> 1) * 64;
  const int wc   = (wv & 1) * (NF * 16);
  const int fr   = lane & 15;
  const int fq   = lane >> 4;

  for (int ks = 0; ks < ksteps; ++ks) {
    stage_tileT<NF>(A, lda, m0, B, ldb, n0, k0 + ks * 64, As, Bs, tid);
    __syncthreads();
    compute_stepT<NF>(As, Bs, wr, wc, fr, fq, acc);
    __syncthreads();
  }
}

// GEMM1 (folded): C1[row][z][bi] bf16 = F2 @ {E|O}^T, K=2048.
// NOTE layout: partials for one row are contiguous (row stride = splitk*2048)
__global__ __launch_bounds__(256) void gemm1_kernel(const __hip_bfloat16* __restrict__ F2,
                                                    const __hip_bfloat16* __restrict__ E,
                                                    const __hip_bfloat16* __restrict__ O,
                                                    __hip_bfloat16* __restrict__ C1,
                                                    int kchunk, int splitk) {
  __shared__ __hip_bfloat16 As[128 * 64];
  __shared__ __hip_bfloat16 Bs[128 * 64];
  int n0 = blockIdx.x * 128;
  int m0 = blockIdx.y * 128;
  int k0 = blockIdx.z * kchunk;
  const __hip_bfloat16* B = (m0 < 256) ? E : O;
  f32x4 acc[4][4];
#pragma unroll
  for (int m = 0; m < 4; ++m)
#pragma unroll
    for (int n = 0; n < 4; ++n)
#pragma unroll
      for (int r = 0; r < 4; ++r) acc[m][n][r] = 0.f;

  gemm_coreT<4>(F2, 2048, m0, B, 2048, n0, k0, kchunk >> 6, As, Bs, acc);

  const int lane = threadIdx.x & 63;
  const int wv   = threadIdx.x >> 6;
  const int wr   = (wv >> 1) * 64, wc = (wv & 1) * 64;
  const int fr   = lane & 15, fq = lane >> 4;
#pragma unroll
  for (int m = 0; m < 4; ++m)
#pragma unroll
    for (int n = 0; n < 4; ++n)
#pragma unroll
      for (int j = 0; j < 4; ++j) {
        int row = m0 + wr + m * 16 + fq * 4 + j;
        int col = n0 + wc + n * 16 + fr;
        C1[((size_t)row * splitk + blockIdx.z) * 2048 + col] = __float2bfloat16(acc[m][n][j]);
      }
}

// ---------------------------------------------------------------------------
// Mode mix v3: contiguous per-row split-K reduce, q=2 (16 batches/block),
// bf16 weights staged once, Hermitian-fold rank-1 correction.
// grid (257, 2) x 256 thr
// ---------------------------------------------------------------------------
__global__ __launch_bounds__(256) void mix_kernel(const __hip_bfloat16* __restrict__ C1,
                                                  const float* __restrict__ Xr256p,
                                                  const float* __restrict__ x2048f,
                                                  const __hip_bfloat16* __restrict__ Wb,
                                                  const float* __restrict__ Sr,
                                                  const float* __restrict__ Si,
                                                  __hip_bfloat16* __restrict__ Y2T,
                                                  __hip_bfloat16* __restrict__ Yx,
                                                  int splitk) {
  const int k = blockIdx.x;   // 0..256
  const int q = blockIdx.y;   // 0..1 (batches q*16 .. +16)
  const int tid = threadIdx.x;
  __shared__ float wlr[4096];
  __shared__ float wli[4096];
  __shared__ float xs[2048];   // [0..1023]=real, [1024..2047]=imag; local bi

  // stage weights for mode k: 16 KB bf16 -> fp32 LDS (read ONCE per (k,q))
  const __hip_bfloat16* wbg = Wb + (size_t)k * 8192;
  for (int c = tid; c < 1024; c += 256) {
    short8 v = *(const short8*)(wbg + c * 8);
    float* dst = (c < 512) ? &wlr[c * 8] : &wli[(c - 512) * 8];
#pragma unroll
    for (int j = 0; j < 8; ++j) {
      unsigned short u = (unsigned short)v[j];
      dst[j] = __bfloat162float(*(__hip_bfloat16*)&u);
    }
  }

  // split-K reduce: thread covers 8 contiguous bi of one part; C1 row is
  // contiguous [splitk][2048] -> strides of 4 KB, not 2 MB.
  {
    const int part = tid >> 7;        // 0=real, 1=imag
    const int ln   = tid & 127;       // 8 bi each -> 1024 bi
    const int bi0  = q * 1024 + ln * 8;
    float f[8] = {0.f, 0.f, 0.f, 0.f, 0.f, 0.f, 0.f, 0.f};
    if (k < 256) {
      if (part == 0 || k > 0) {
        int row = part ? 255 + k : k;
        const __hip_bfloat16* src = C1 + (size_t)row * splitk * 2048 + bi0;
        for (int z = 0; z < splitk; ++z) {
          short8 v = *(const short8*)(src + (size_t)z * 2048);
#pragma unroll
          for (int j = 0; j < 8; ++j) {
            unsigned short u = (unsigned short)v[j];
            f[j] += __bfloat162float(*(__hip_bfloat16*)&u);
          }
        }
      }
      if (part == 0) {
        float par = (k & 1) ? -1.f : 1.f;   // cos(k*pi)
#pragma unroll
        for (int j = 0; j < 8; ++j) f[j] += par * x2048f[bi0 + j];
      }
    } else {
      if (part == 0) {
        const float* sp = Xr256p + (size_t)(bi0 >> 6) * 2048 + (bi0 & 63);
#pragma unroll 8
        for (int nt = 0; nt < 32; ++nt)
#pragma unroll
          for (int j = 0; j < 8; ++j) f[j] += sp[nt * 64 + j];
      } else {
        const __hip_bfloat16* src = C1 + (size_t)511 * splitk * 2048 + bi0;
        for (int z = 0; z < splitk; ++z) {
          short8 v = *(const short8*)(src + (size_t)z * 2048);
#pragma unroll
          for (int j = 0; j < 8; ++j) {
            unsigned short u = (unsigned short)v[j];
            f[j] += __bfloat162float(*(__hip_bfloat16*)&u);
          }
        }
      }
    }
#pragma unroll
    for (int j = 0; j < 8; ++j) xs[part * 1024 + ln * 8 + j] = f[j];
  }
  __syncthreads();

  const int o  = tid & 63;
  const int jj = tid >> 6;          // 0..3 -> 4 batches each
  float pr[4] = {0.f, 0.f, 0.f, 0.f};
  float pi[4] = {0.f, 0.f, 0.f, 0.f};
#pragma unroll 4
  for (int i = 0; i < 64; ++i) {
    float wrv = wlr[i * 64 + o];
    float wiv = wli[i * 64 + o];
#pragma unroll
    for (int u = 0; u < 4; ++u) {
      int lb = (jj * 4 + u) * 64 + i;
      float xr = xs[lb], xi = xs[1024 + lb];
      pr[u] += xr * wrv - xi * wiv;
      pi[u] += xr * wiv + xi * wrv;
    }
  }
#pragma unroll
  for (int u = 0; u < 4; ++u) {
    int b = q * 16 + jj * 4 + u;
    float sr = Sr[b * 257 + k], si = Si[b * 257 + k];
    int bo = b * 64 + o;
    __hip_bfloat16 yr = __float2bfloat16(pr[u] * sr - pi[u] * si);
    __hip_bfloat16 yi = __float2bfloat16(pr[u] * si + pi[u] * sr);
    if (k < 256) Y2T[(size_t)bo * 512 + k] = yr;
    else         Yx[bo] = yr;
    if (k >= 1)  Y2T[(size_t)bo * 512 + 255 + k] = yi;
  }
}

// GEMM2 (folded): rows n=0..2047. accC over cos K-half (+ g*Yx), accS over sin K-half.
// out[n] = accC - accS ; out[4096-n] = accC + accS (n>=1) ; out[2048] = alt-sum (m0==0)
__global__ __launch_bounds__(256) void gemm2_kernel(const __hip_bfloat16* __restrict__ Gm2,
                                                    const __hip_bfloat16* __restrict__ Y2T,
                                                    const __hip_bfloat16* __restrict__ Yx,
                                                    float* __restrict__ out) {
  __shared__ __hip_bfloat16 As[128 * 64];
  __shared__ __hip_bfloat16 Bs[64 * 64];
  __shared__ float red2[4][64];
  int n0 = blockIdx.x * 64;    // bo
  int m0 = blockIdx.y * 128;   // n (time), 0..1920
  f32x4 accC[4][2], accS[4][2];
#pragma unroll
  for (int m = 0; m < 4; ++m)
#pragma unroll
    for (int n = 0; n < 2; ++n)
#pragma unroll
      for (int r = 0; r < 4; ++r) { accC[m][n][r] = 0.f; accS[m][n][r] = 0.f; }

  gemm_coreT<2>(Gm2, 512, m0, Y2T, 512, n0, 0,   4, As, Bs, accC);
  gemm_coreT<2>(Gm2, 512, m0, Y2T, 512, n0, 256, 4, As, Bs, accS);

  const int lane = threadIdx.x & 63;
  const int wv   = threadIdx.x >> 6;
  const int wr   = (wv >> 1) * 64, wc = (wv & 1) * 32;
  const int fr   = lane & 15, fq = lane >> 4;
  float yx[2];
#pragma unroll
  for (int n = 0; n < 2; ++n)
    yx[n] = __bfloat162float(Yx[n0 + wc + n * 16 + fr]);
#pragma unroll
  for (int m = 0; m < 4; ++m)
#pragma unroll
    for (int j = 0; j < 4; ++j) {
      int row = m0 + wr + m * 16 + fq * 4 + j;   // n index 0..2047
      float g = cos_rev((float)(row & 15) * INV16);
#pragma unroll
      for (int n = 0; n < 2; ++n) {
        int col = n0 + wc + n * 16 + fr;         // bo index
        int b = col >> 6, o = col & 63;
        float vC = accC[m][n][j] + g * yx[n];
        float vS = accS[m][n][j];
        out[((size_t)b * 4096 + row) * 64 + o] = vC - vS;
        if (row > 0)
          out[((size_t)b * 4096 + (4096 - row)) * 64 + o] = vC + vS;
      }
    }

  if (m0 == 0) {
    __syncthreads();
    const int tid = threadIdx.x;
    int col = tid & 63, grp = tid >> 6;
    int bo = n0 + col;
    float s = 0.f;
    for (int k = grp * 64; k < grp * 64 + 64; ++k) {
      float v = __bfloat162float(Y2T[(size_t)bo * 512 + k]);
      s += (k & 1) ? -v : v;
    }
    red2[grp][col] = s;
    __syncthreads();
    if (tid < 64) {
      int bo2 = n0 + tid;
      float alt = red2[0][tid] + red2[1][tid] + red2[2][tid] + red2[3][tid]
                + __bfloat162float(Yx[bo2]);
      int b = bo2 >> 6, o = bo2 & 63;
      out[((size_t)b * 4096 + 2048) * 64 + o] = alt;
    }
  }
}

// ---------------------------------------------------------------------------
extern "C" void kernel_launch(void* const* d_in, const int* in_sizes, int n_in,
                              void* d_out, int out_size, void* d_ws, size_t ws_size,
                              hipStream_t stream) {
  const float* x  = (const float*)d_in[0];   // (32,4096,64)
  const float* te = (const float*)d_in[1];   // (32,256)
  const float* wr = (const float*)d_in[2];   // (257,64,64)
  const float* wi = (const float*)d_in[3];
  const float* dr = (const float*)d_in[4];   // (256,257)
  const float* di = (const float*)d_in[5];
  float* out = (float*)d_out;

  char* p = (char*)d_ws;
  auto alloc = [&](size_t bytes) -> char* {
    char* r = p;
    p += (bytes + 255) & ~(size_t)255;
    return r;
  };
  __hip_bfloat16* F2  = (__hip_bfloat16*)alloc(512ull * 2048 * 2);
  __hip_bfloat16* Gm2 = (__hip_bfloat16*)alloc(2048ull * 512 * 2);
  __hip_bfloat16* E   = (__hip_bfloat16*)alloc(2048ull * 2048 * 2);
  __hip_bfloat16* O   = (__hip_bfloat16*)alloc(2048ull * 2048 * 2);
  float* Xr256p = (float*)alloc(32ull * 32 * 64 * 4);   // [b][nt 32][i]
  float* x2048f = (float*)alloc(2048 * 4);
  float* Sr = (float*)alloc(32 * 257 * 4);
  float* Si = (float*)alloc(32 * 257 * 4);
  __hip_bfloat16* Y2T = (__hip_bfloat16*)alloc(2048ull * 512 * 2);
  __hip_bfloat16* Yx  = (__hip_bfloat16*)alloc(2048 * 2);
  __hip_bfloat16* Wb  = (__hip_bfloat16*)alloc(257ull * 8192 * 2);
  size_t fixed = (size_t)(p - (char*)d_ws);

  int splitk = 2;
  if (ws_size >= fixed + 8ull * 512 * 2048 * 2)      splitk = 8;
  else if (ws_size >= fixed + 4ull * 512 * 2048 * 2) splitk = 4;
  __hip_bfloat16* C1 = (__hip_bfloat16*)alloc((size_t)splitk * 512 * 2048 * 2);
  int kchunk = 2048 / splitk;

  prep_kernel<<<3108, 256, 0, stream>>>(F2, Gm2, te, dr, di, Sr, Si, x, E, O,
                                        Xr256p, x2048f, wr, wi, Wb);
  gemm1_kernel<<<dim3(16, 4, splitk), 256, 0, stream>>>(F2, E, O, C1, kchunk, splitk);
  mix_kernel<<<dim3(257, 2), 256, 0, stream>>>(C1, Xr256p, x2048f, Wb, Sr, Si, Y2T, Yx, splitk);
  gemm2_kernel<<<dim3(32, 16), 256, 0, stream>>>(Gm2, Y2T, Yx, out);
}